// Round 3
// baseline (103.441 us; speedup 1.0000x reference)
//
#include <hip/hip_runtime.h>
#include <math.h>

__device__ __forceinline__ float tanh_fast(float v) {
    v = fminf(15.f, fmaxf(-15.f, v));
    float e = __expf(2.f * v);
    return (e - 1.f) * __builtin_amdgcn_rcpf(e + 1.f);
}

// Packed LDS weight buffer — every segment 16B-aligned (float4-divisible sizes):
#define O_W1  0     // 216
#define O_B1  216   // 6  (pad to 224)
#define O_W2  224   // 72
#define O_B2  296   // 4
#define O_W3  300   // 48
#define O_B3  348   // 4
#define O_E1W 352   // 24
#define O_E1B 376   // 4
#define O_E2W 380   // 16
#define O_E2B 396   // 4
#define O_D1W 400   // 48
#define O_D1B 448   // 4
#define O_D2W 452   // 24
#define O_D2B 476   // 2 (pad to 480)
#define O_D3W 480   // 12
#define O_D3B 492   // 2 (pad to 496)
#define O_D4W 496   // 252
#define O_D4B 748   // 6

__global__ __launch_bounds__(64) void convpolicy_kernel(
    const float* __restrict__ x,
    const float* __restrict__ w1, const float* __restrict__ b1,
    const float* __restrict__ w2, const float* __restrict__ b2,
    const float* __restrict__ w3, const float* __restrict__ b3,
    const float* __restrict__ e1w, const float* __restrict__ e1b,
    const float* __restrict__ e2w, const float* __restrict__ e2b,
    const float* __restrict__ d1w, const float* __restrict__ d1b,
    const float* __restrict__ d2w, const float* __restrict__ d2b,
    const float* __restrict__ d3w, const float* __restrict__ d3b,
    const float* __restrict__ d4w, const float* __restrict__ d4b,
    float* __restrict__ out)
{
    __shared__ __align__(16) float wbuf[756];
    __shared__ __align__(16) float xbuf[192];
    __shared__ float jcat[180];   // (12,15)
    __shared__ float fmc1[78];    // (6,13)
    __shared__ float dsb[30];     // (6,5)
    __shared__ float fmc2[12];    // (4,3)
    __shared__ float embin[6];
    __shared__ float emb1v[4];
    __shared__ float emb2v[4];
    __shared__ float dc1[12];     // (4,3)
    __shared__ float dc2[10];     // (2,5)
    __shared__ float usb[26];     // (2,13)
    __shared__ float dc3[30];     // (2,15)
    __shared__ float at2[2];

    const int l = threadIdx.x;

    // ---- prefetch: all global loads, compile-time segment map, float4 ----
    if (l < 54) *(float4*)(wbuf + O_W1  + 4 * l) = ((const float4*)w1)[l];
    if (l < 63) *(float4*)(wbuf + O_D4W + 4 * l) = ((const float4*)d4w)[l];
    if (l < 18)      *(float4*)(wbuf + O_W2  + 4 * l)        = ((const float4*)w2)[l];
    else if (l < 30) *(float4*)(wbuf + O_W3  + 4 * (l - 18)) = ((const float4*)w3)[l - 18];
    else if (l < 42) *(float4*)(wbuf + O_D1W + 4 * (l - 30)) = ((const float4*)d1w)[l - 30];
    else if (l < 48) *(float4*)(wbuf + O_E1W + 4 * (l - 42)) = ((const float4*)e1w)[l - 42];
    else if (l < 54) *(float4*)(wbuf + O_D2W + 4 * (l - 48)) = ((const float4*)d2w)[l - 48];
    else if (l < 58) *(float4*)(wbuf + O_E2W + 4 * (l - 54)) = ((const float4*)e2w)[l - 54];
    else if (l < 61) *(float4*)(wbuf + O_D3W + 4 * (l - 58)) = ((const float4*)d3w)[l - 58];
    if (l < 6)       wbuf[O_B1  + l]      = b1[l];
    else if (l < 10) wbuf[O_B2  + l - 6]  = b2[l - 6];
    else if (l < 14) wbuf[O_B3  + l - 10] = b3[l - 10];
    else if (l < 18) wbuf[O_E1B + l - 14] = e1b[l - 14];
    else if (l < 22) wbuf[O_E2B + l - 18] = e2b[l - 18];
    else if (l < 26) wbuf[O_D1B + l - 22] = d1b[l - 22];
    else if (l < 28) wbuf[O_D2B + l - 26] = d2b[l - 26];
    else if (l < 30) wbuf[O_D3B + l - 28] = d3b[l - 28];
    else if (l < 36) wbuf[O_D4B + l - 30] = d4b[l - 30];
    if (l < 47)      *(float4*)(xbuf + 4 * l) = ((const float4*)x)[l];
    else if (l == 47) xbuf[188] = x[188];
    __syncthreads();

    // ---- psi: two atan2f in SIMT-parallel on lanes 0/1 ----
    if (l < 2) {
        float yy = (l == 0) ? xbuf[6] : -xbuf[4];   // qz | -qx
        float xx = (l == 0) ? xbuf[3] : xbuf[5];    // qw |  qy
        at2[l] = atan2f(yy, xx);
    }
    // ---- jcat (12,15) from xbuf ----
    #pragma unroll
    for (int r = 0; r < 3; ++r) {
        int g = l + 64 * r;
        if (g < 180) {
            float v;
            if (g < 90) v = (g < 2) ? 0.f : xbuf[5 + g];
            else { int f = g - 90; v = (f < 2) ? 0.f : xbuf[99 + f]; }
            jcat[g] = v;
        }
    }
    __syncthreads();

    // ---- conv1 (6,12,3): (12,15) -> (6,13), tanh ----
    #pragma unroll
    for (int r = 0; r < 2; ++r) {
        int g = l + 64 * r;
        if (g < 78) {
            int o = g / 13, i = g % 13;
            float acc = wbuf[O_B1 + o];
            const float* wr = wbuf + O_W1 + o * 36;
            #pragma unroll
            for (int c = 0; c < 12; ++c)
                #pragma unroll
                for (int k = 0; k < 3; ++k)
                    acc += wr[c * 3 + k] * jcat[c * 15 + i + k];
            fmc1[g] = tanh_fast(acc);
        }
    }
    __syncthreads();

    // ---- adaptive avg pool 13 -> 5 ----
    if (l < 30) {
        int c = l / 5, o = l % 5;
        int s = (o * 13) / 5;
        int e = ((o + 1) * 13 + 4) / 5;
        float acc = 0.f;
        for (int i = s; i < e; ++i) acc += fmc1[c * 13 + i];
        dsb[l] = acc / (float)(e - s);
    }
    __syncthreads();

    // ---- conv2 (4,6,3): (6,5) -> (4,3), tanh ----
    if (l < 12) {
        int o = l / 3, i = l % 3;
        float acc = wbuf[O_B2 + o];
        const float* wr = wbuf + O_W2 + o * 18;
        #pragma unroll
        for (int c = 0; c < 6; ++c)
            #pragma unroll
            for (int k = 0; k < 3; ++k)
                acc += wr[c * 3 + k] * dsb[c * 5 + i + k];
        fmc2[l] = tanh_fast(acc);
    }
    __syncthreads();

    // ---- conv3 (4,4,3): (4,3) -> (4,1); build embin ----
    if (l < 4) {
        float acc = wbuf[O_B3 + l];
        const float* wr = wbuf + O_W3 + l * 12;
        #pragma unroll
        for (int c = 0; c < 4; ++c)
            #pragma unroll
            for (int k = 0; k < 3; ++k)
                acc += wr[c * 3 + k] * fmc2[c * 3 + k];
        embin[l] = tanh_fast(acc);
    } else if (l == 4) {
        embin[4] = at2[0] - at2[1];   // psi
    } else if (l == 5) {
        embin[5] = xbuf[100];
    }
    __syncthreads();

    // ---- emb1 (4,6,1), tanh ----
    if (l < 4) {
        float acc = wbuf[O_E1B + l];
        #pragma unroll
        for (int c = 0; c < 6; ++c) acc += wbuf[O_E1W + l * 6 + c] * embin[c];
        emb1v[l] = tanh_fast(acc);
    }
    __syncthreads();

    // ---- emb2 (4,4,1), tanh ----
    if (l < 4) {
        float acc = wbuf[O_E2B + l];
        #pragma unroll
        for (int c = 0; c < 4; ++c) acc += wbuf[O_E2W + l * 4 + c] * emb1v[c];
        emb2v[l] = tanh_fast(acc);
    }
    __syncthreads();

    // ---- dec1 convT (4,4,3): (4,1) -> (4,3), tanh ----
    if (l < 12) {
        int o = l / 3, t = l % 3;
        float acc = wbuf[O_D1B + o];
        #pragma unroll
        for (int c = 0; c < 4; ++c)
            acc += wbuf[O_D1W + c * 12 + o * 3 + t] * emb2v[c];
        dc1[l] = tanh_fast(acc);
    }
    __syncthreads();

    // ---- dec2 convT (4,2,3): (4,3) -> (2,5), tanh ----
    if (l < 10) {
        int o = l / 5, t = l % 5;
        float acc = wbuf[O_D2B + o];
        int ilo = (t - 2 > 0) ? t - 2 : 0;
        int ihi = (t < 2) ? t : 2;
        for (int c = 0; c < 4; ++c)
            for (int i = ilo; i <= ihi; ++i)
                acc += wbuf[O_D2W + c * 6 + o * 3 + (t - i)] * dc1[c * 3 + i];
        dc2[l] = tanh_fast(acc);
    }
    __syncthreads();

    // ---- upsample 5 -> 13 ----
    if (l < 26) {
        int c = l / 13, i = l % 13;
        usb[l] = dc2[c * 5 + (i * 5) / 13];
    }
    __syncthreads();

    // ---- dec3 convT (2,2,3): (2,13) -> (2,15), tanh ----
    if (l < 30) {
        int o = l / 15, t = l % 15;
        float acc = wbuf[O_D3B + o];
        int ilo = (t - 2 > 0) ? t - 2 : 0;
        int ihi = (t < 12) ? t : 12;
        for (int c = 0; c < 2; ++c)
            for (int i = ilo; i <= ihi; ++i)
                acc += wbuf[O_D3W + c * 6 + o * 3 + (t - i)] * usb[c * 13 + i];
        dc3[l] = tanh_fast(acc);
    }
    __syncthreads();

    // ---- dec4 convT (14,6,3) pad=1: (14,15) -> (6,15); out = flat[2:] ----
    #pragma unroll
    for (int r = 0; r < 2; ++r) {
        int idx = l + 64 * r;
        if (idx < 88) {
            int g = idx + 2;
            int o = g / 15, t = g % 15;
            float acc = wbuf[O_D4B + o];
            int ilo = (t - 1 > 0) ? t - 1 : 0;
            int ihi = (t + 1 < 14) ? t + 1 : 14;
            for (int c = 0; c < 14; ++c) {
                const float* src = (c < 2) ? (dc3 + c * 15) : (jcat + (c - 2) * 15);
                for (int i = ilo; i <= ihi; ++i)
                    acc += wbuf[O_D4W + c * 18 + o * 3 + (t - i + 1)] * src[i];
            }
            out[idx] = acc;
        }
    }
}

extern "C" void kernel_launch(void* const* d_in, const int* in_sizes, int n_in,
                              void* d_out, int out_size, void* d_ws, size_t ws_size,
                              hipStream_t stream) {
    const float* x   = (const float*)d_in[0];
    const float* w1  = (const float*)d_in[1];
    const float* b1  = (const float*)d_in[2];
    const float* w2  = (const float*)d_in[3];
    const float* b2  = (const float*)d_in[4];
    const float* w3  = (const float*)d_in[5];
    const float* b3  = (const float*)d_in[6];
    const float* e1w = (const float*)d_in[7];
    const float* e1b = (const float*)d_in[8];
    const float* e2w = (const float*)d_in[9];
    const float* e2b = (const float*)d_in[10];
    const float* d1w = (const float*)d_in[11];
    const float* d1b = (const float*)d_in[12];
    const float* d2w = (const float*)d_in[13];
    const float* d2b = (const float*)d_in[14];
    const float* d3w = (const float*)d_in[15];
    const float* d3b = (const float*)d_in[16];
    const float* d4w = (const float*)d_in[17];
    const float* d4b = (const float*)d_in[18];
    float* out = (float*)d_out;

    convpolicy_kernel<<<1, 64, 0, stream>>>(
        x, w1, b1, w2, b2, w3, b3, e1w, e1b, e2w, e2b,
        d1w, d1b, d2w, d2b, d3w, d3b, d4w, d4b, out);
}

// Round 4
// 97.738 us; speedup vs baseline: 1.0583x; 1.0583x over previous
//
#include <hip/hip_runtime.h>
#include <math.h>

__device__ __forceinline__ float tanh_fast(float v) {
    v = fminf(15.f, fmaxf(-15.f, v));
    float e = __expf(2.f * v);
    return (e - 1.f) * __builtin_amdgcn_rcpf(e + 1.f);
}

// Packed LDS weight buffer — every float4 segment 16B-aligned:
#define O_W1  0     // 216
#define O_B1  216   // 6  (pad to 224)
#define O_W2  224   // 72
#define O_B2  296   // 4
#define O_W3  300   // 48
#define O_B3  348   // 4
#define O_E1W 352   // 24
#define O_E1B 376   // 4
#define O_E2W 380   // 16
#define O_E2B 396   // 4
#define O_D1W 400   // 48
#define O_D1B 448   // 4
#define O_D2W 452   // 24
#define O_D2B 476   // 2 (pad to 480)
#define O_D3W 480   // 12
#define O_D3B 492   // 2 (pad to 496)
#define O_D4W 496   // 252
#define O_D4B 748   // 6   total 754 (alloc 756)

__global__ __launch_bounds__(128) void convpolicy_kernel(
    const float* __restrict__ x,
    const float* __restrict__ w1, const float* __restrict__ b1,
    const float* __restrict__ w2, const float* __restrict__ b2,
    const float* __restrict__ w3, const float* __restrict__ b3,
    const float* __restrict__ e1w, const float* __restrict__ e1b,
    const float* __restrict__ e2w, const float* __restrict__ e2b,
    const float* __restrict__ d1w, const float* __restrict__ d1b,
    const float* __restrict__ d2w, const float* __restrict__ d2b,
    const float* __restrict__ d3w, const float* __restrict__ d3b,
    const float* __restrict__ d4w, const float* __restrict__ d4b,
    float* __restrict__ out)
{
    __shared__ __align__(16) float wbuf[756];
    __shared__ float jcat[180];   // (12,15)
    __shared__ float fmc1[78];    // (6,13)
    __shared__ float dsb[30];     // (6,5)
    __shared__ float fmc2[12];    // (4,3)
    __shared__ float embin[6];
    __shared__ float emb1v[4];
    __shared__ float emb2v[4];
    __shared__ float dc1[12];     // (4,3)
    __shared__ float dc2[10];     // (2,5)
    __shared__ float usb[26];     // (2,13)
    __shared__ float dc3[30];     // (2,15)
    __shared__ float at2[2];
    __shared__ float xv100;

    const int l = threadIdx.x;

    // ================= prefetch: everything global, one latency round ======
    #define W4(OFF, SRC, IDX) *(float4*)(wbuf + (OFF) + 4 * (IDX)) = ((const float4*)(SRC))[(IDX)]
    // float4 batch 1 (117 lane-slots) + first biases
    if (l < 54)        { W4(O_W1,  w1,  l); }
    else if (l < 117)  { W4(O_D4W, d4w, l - 54); }
    else {                                   // lanes 117..127
        int m = l - 117;
        if (m < 6)       wbuf[O_B1 + m]     = b1[m];
        else if (m < 10) wbuf[O_B2 + m - 6] = b2[m - 6];
        else             wbuf[O_B3]         = b3[0];     // lane 127
    }
    // float4 batch 2 (61 slots) + remaining biases on idle lanes
    if (l < 18)       { W4(O_W2,  w2,  l); }
    else if (l < 30)  { W4(O_W3,  w3,  l - 18); }
    else if (l < 36)  { W4(O_E1W, e1w, l - 30); }
    else if (l < 40)  { W4(O_E2W, e2w, l - 36); }
    else if (l < 52)  { W4(O_D1W, d1w, l - 40); }
    else if (l < 58)  { W4(O_D2W, d2w, l - 52); }
    else if (l < 61)  { W4(O_D3W, d3w, l - 58); }
    else if (l < 64)  wbuf[O_B3  + (l - 60)] = b3[l - 60];   // b3[1..3]
    else if (l < 68)  wbuf[O_E1B + l - 64] = e1b[l - 64];
    else if (l < 72)  wbuf[O_E2B + l - 68] = e2b[l - 68];
    else if (l < 76)  wbuf[O_D1B + l - 72] = d1b[l - 72];
    else if (l < 78)  wbuf[O_D2B + l - 76] = d2b[l - 76];
    else if (l < 80)  wbuf[O_D3B + l - 78] = d3b[l - 78];
    else if (l < 86)  wbuf[O_D4B + l - 80] = d4b[l - 80];
    else if (l < 88) {                     // lanes 86/87: parallel atan2
        float yy = (l == 86) ? x[6] : -x[4];   // qz | -qx
        float xx = (l == 86) ? x[3] :  x[5];   // qw |  qy
        at2[l - 86] = atan2f(yy, xx);
    } else if (l == 88) {
        xv100 = x[100];
    }
    #undef W4
    // jcat (12,15) straight from global x, concurrent with the above
    {
        if (l < 90)  jcat[l] = (l < 2) ? 0.f : x[5 + l];            // jl
        else if (l < 128) { int f = l - 90; jcat[l] = (f < 2) ? 0.f : x[99 + f]; }
        int g = l + 128;                                            // 128..179
        if (g < 180) { int f = g - 90; jcat[g] = (f < 2) ? 0.f : x[99 + f]; }
    }
    __syncthreads();

    // ---- conv1 (6,12,3): (12,15) -> (6,13), tanh — one round, 78 lanes ----
    if (l < 78) {
        int o = l / 13, i = l % 13;
        float acc = wbuf[O_B1 + o];
        const float* wr = wbuf + O_W1 + o * 36;
        #pragma unroll
        for (int c = 0; c < 12; ++c)
            #pragma unroll
            for (int k = 0; k < 3; ++k)
                acc += wr[c * 3 + k] * jcat[c * 15 + i + k];
        fmc1[l] = tanh_fast(acc);
    }
    __syncthreads();

    // ---- adaptive avg pool 13 -> 5 ----
    if (l < 30) {
        int c = l / 5, o = l % 5;
        int s = (o * 13) / 5;
        int e = ((o + 1) * 13 + 4) / 5;
        float acc = 0.f;
        for (int i = s; i < e; ++i) acc += fmc1[c * 13 + i];
        dsb[l] = acc / (float)(e - s);
    }
    __syncthreads();

    // ---- conv2 (4,6,3): (6,5) -> (4,3), tanh ----
    if (l < 12) {
        int o = l / 3, i = l % 3;
        float acc = wbuf[O_B2 + o];
        const float* wr = wbuf + O_W2 + o * 18;
        #pragma unroll
        for (int c = 0; c < 6; ++c)
            #pragma unroll
            for (int k = 0; k < 3; ++k)
                acc += wr[c * 3 + k] * dsb[c * 5 + i + k];
        fmc2[l] = tanh_fast(acc);
    }
    __syncthreads();

    // ---- conv3 (4,4,3): (4,3) -> (4,1); build embin ----
    if (l < 4) {
        float acc = wbuf[O_B3 + l];
        const float* wr = wbuf + O_W3 + l * 12;
        #pragma unroll
        for (int c = 0; c < 4; ++c)
            #pragma unroll
            for (int k = 0; k < 3; ++k)
                acc += wr[c * 3 + k] * fmc2[c * 3 + k];
        embin[l] = tanh_fast(acc);
    } else if (l == 4) {
        embin[4] = at2[0] - at2[1];   // psi
    } else if (l == 5) {
        embin[5] = xv100;
    }
    __syncthreads();

    // ---- emb1 (4,6,1), tanh ----
    if (l < 4) {
        float acc = wbuf[O_E1B + l];
        #pragma unroll
        for (int c = 0; c < 6; ++c) acc += wbuf[O_E1W + l * 6 + c] * embin[c];
        emb1v[l] = tanh_fast(acc);
    }
    __syncthreads();

    // ---- emb2 (4,4,1), tanh ----
    if (l < 4) {
        float acc = wbuf[O_E2B + l];
        #pragma unroll
        for (int c = 0; c < 4; ++c) acc += wbuf[O_E2W + l * 4 + c] * emb1v[c];
        emb2v[l] = tanh_fast(acc);
    }
    __syncthreads();

    // ---- dec1 convT (4,4,3): (4,1) -> (4,3), tanh ----
    if (l < 12) {
        int o = l / 3, t = l % 3;
        float acc = wbuf[O_D1B + o];
        #pragma unroll
        for (int c = 0; c < 4; ++c)
            acc += wbuf[O_D1W + c * 12 + o * 3 + t] * emb2v[c];
        dc1[l] = tanh_fast(acc);
    }
    __syncthreads();

    // ---- dec2 convT (4,2,3): (4,3) -> (2,5), tanh ----
    if (l < 10) {
        int o = l / 5, t = l % 5;
        float acc = wbuf[O_D2B + o];
        int ilo = (t - 2 > 0) ? t - 2 : 0;
        int ihi = (t < 2) ? t : 2;
        for (int c = 0; c < 4; ++c)
            for (int i = ilo; i <= ihi; ++i)
                acc += wbuf[O_D2W + c * 6 + o * 3 + (t - i)] * dc1[c * 3 + i];
        dc2[l] = tanh_fast(acc);
    }
    __syncthreads();

    // ---- upsample 5 -> 13 ----
    if (l < 26) {
        int c = l / 13, i = l % 13;
        usb[l] = dc2[c * 5 + (i * 5) / 13];
    }
    __syncthreads();

    // ---- dec3 convT (2,2,3): (2,13) -> (2,15), tanh ----
    if (l < 30) {
        int o = l / 15, t = l % 15;
        float acc = wbuf[O_D3B + o];
        int ilo = (t - 2 > 0) ? t - 2 : 0;
        int ihi = (t < 12) ? t : 12;
        for (int c = 0; c < 2; ++c)
            for (int i = ilo; i <= ihi; ++i)
                acc += wbuf[O_D3W + c * 6 + o * 3 + (t - i)] * usb[c * 13 + i];
        dc3[l] = tanh_fast(acc);
    }
    __syncthreads();

    // ---- dec4 convT (14,6,3) pad=1: (14,15)->(6,15); out = flat[2:] — one round ----
    if (l < 88) {
        int g = l + 2;
        int o = g / 15, t = g % 15;
        float acc = wbuf[O_D4B + o];
        int ilo = (t - 1 > 0) ? t - 1 : 0;
        int ihi = (t + 1 < 14) ? t + 1 : 14;
        for (int c = 0; c < 14; ++c) {
            const float* src = (c < 2) ? (dc3 + c * 15) : (jcat + (c - 2) * 15);
            for (int i = ilo; i <= ihi; ++i)
                acc += wbuf[O_D4W + c * 18 + o * 3 + (t - i + 1)] * src[i];
        }
        out[l] = acc;
    }
}

extern "C" void kernel_launch(void* const* d_in, const int* in_sizes, int n_in,
                              void* d_out, int out_size, void* d_ws, size_t ws_size,
                              hipStream_t stream) {
    const float* x   = (const float*)d_in[0];
    const float* w1  = (const float*)d_in[1];
    const float* b1  = (const float*)d_in[2];
    const float* w2  = (const float*)d_in[3];
    const float* b2  = (const float*)d_in[4];
    const float* w3  = (const float*)d_in[5];
    const float* b3  = (const float*)d_in[6];
    const float* e1w = (const float*)d_in[7];
    const float* e1b = (const float*)d_in[8];
    const float* e2w = (const float*)d_in[9];
    const float* e2b = (const float*)d_in[10];
    const float* d1w = (const float*)d_in[11];
    const float* d1b = (const float*)d_in[12];
    const float* d2w = (const float*)d_in[13];
    const float* d2b = (const float*)d_in[14];
    const float* d3w = (const float*)d_in[15];
    const float* d3b = (const float*)d_in[16];
    const float* d4w = (const float*)d_in[17];
    const float* d4b = (const float*)d_in[18];
    float* out = (float*)d_out;

    convpolicy_kernel<<<1, 128, 0, stream>>>(
        x, w1, b1, w2, b2, w3, b3, e1w, e1b, e2w, e2b,
        d1w, d1b, d2w, d2b, d3w, d3b, d4w, d4b, out);
}